// Round 4
// baseline (26.174 us; speedup 1.0000x reference)
//
#include <hip/hip_runtime.h>

// RBFLayer: B=4, N=16384, D=16, K=64
//   s  = scaling[0,0,:,0]            (D,)
//   Hx = x * s                       (B,N,D)
//   O[b,n,k] = sum_d (Hx[b,n,d] - s[d]*centers[k,d])^2
// Outputs concatenated: O (B*N*K floats) then Hx (B*N*D floats).
//
// Structure: lane = center index k (scaled center row in 16 VGPRs).
// x tile staged scaled into LDS (minimal pre-barrier path: 1 float4 load,
// 4 mul, 1 ds_write_b128). Hx stored from the retained register AFTER the
// compute loop so no global store sits before the barrier's vmcnt drain.

constexpr int D = 16;
constexpr int K = 64;
constexpr int ROWS_PER_BLOCK = 64;   // 1024 floats = 1 float4/thread
constexpr int BLOCK = 256;

__global__ __launch_bounds__(BLOCK) void rbf_kernel(
    const float* __restrict__ x,        // (rows, D)
    const float* __restrict__ centers,  // (K, D)
    const float* __restrict__ scaling,  // (D,)
    float* __restrict__ O,              // (rows, K)
    float* __restrict__ Hx,             // (rows, D)
    int nRows)
{
    const int tid  = threadIdx.x;
    const int lane = tid & 63;          // = center index k
    const int wid  = tid >> 6;          // 0..3

    __shared__ float hx_sh[ROWS_PER_BLOCK * D];   // 4 KB

    const int blockRow0 = blockIdx.x * ROWS_PER_BLOCK;

    // ---- s in registers (4 x float4). ----
    const float4* s4p = reinterpret_cast<const float4*>(scaling);
    float4 sv[4];
    #pragma unroll
    for (int q = 0; q < 4; ++q) sv[q] = s4p[q];

    // ---- Minimal staging: 1 float4 of x per thread, scale, ds_write. ----
    float4 h;
    {
        const float4* x4 = reinterpret_cast<const float4*>(x + (size_t)blockRow0 * D);
        float4 v = x4[tid];
        float4 sq = sv[tid & 3];         // quarter of the 16-wide row
        h.x = v.x * sq.x;
        h.y = v.y * sq.y;
        h.z = v.z * sq.z;
        h.w = v.w * sq.w;
        reinterpret_cast<float4*>(hx_sh)[tid] = h;
    }

    // ---- Per-lane scaled center row (16 VGPRs) — overlaps with staging. ----
    float cs[D];
    {
        const float4* c4 = reinterpret_cast<const float4*>(centers + lane * D);
        #pragma unroll
        for (int q = 0; q < 4; ++q) {
            float4 cv = c4[q];
            cs[4 * q + 0] = cv.x * sv[q].x;
            cs[4 * q + 1] = cv.y * sv[q].y;
            cs[4 * q + 2] = cv.z * sv[q].z;
            cs[4 * q + 3] = cv.w * sv[q].w;
        }
    }

    __syncthreads();

    // ---- Compute: wave wid handles rows [wid*16, wid*16+16). ----
    const float4* hx4 = reinterpret_cast<const float4*>(hx_sh);
    #pragma unroll
    for (int r = 0; r < 16; ++r) {
        const int localRow = wid * 16 + r;

        float4 h0 = hx4[localRow * 4 + 0];   // ds_read_b128 broadcast
        float4 h1 = hx4[localRow * 4 + 1];
        float4 h2 = hx4[localRow * 4 + 2];
        float4 h3 = hx4[localRow * 4 + 3];

        float acc = 0.f;
        float d0;
        d0 = h0.x - cs[0];  acc = fmaf(d0, d0, acc);
        d0 = h0.y - cs[1];  acc = fmaf(d0, d0, acc);
        d0 = h0.z - cs[2];  acc = fmaf(d0, d0, acc);
        d0 = h0.w - cs[3];  acc = fmaf(d0, d0, acc);
        d0 = h1.x - cs[4];  acc = fmaf(d0, d0, acc);
        d0 = h1.y - cs[5];  acc = fmaf(d0, d0, acc);
        d0 = h1.z - cs[6];  acc = fmaf(d0, d0, acc);
        d0 = h1.w - cs[7];  acc = fmaf(d0, d0, acc);
        d0 = h2.x - cs[8];  acc = fmaf(d0, d0, acc);
        d0 = h2.y - cs[9];  acc = fmaf(d0, d0, acc);
        d0 = h2.z - cs[10]; acc = fmaf(d0, d0, acc);
        d0 = h2.w - cs[11]; acc = fmaf(d0, d0, acc);
        d0 = h3.x - cs[12]; acc = fmaf(d0, d0, acc);
        d0 = h3.y - cs[13]; acc = fmaf(d0, d0, acc);
        d0 = h3.z - cs[14]; acc = fmaf(d0, d0, acc);
        d0 = h3.w - cs[15]; acc = fmaf(d0, d0, acc);

        O[(size_t)(blockRow0 + localRow) * K + lane] = acc;  // 256B/wave
    }

    // ---- Hx store from retained register (coalesced float4). ----
    reinterpret_cast<float4*>(Hx + (size_t)blockRow0 * D)[tid] = h;
}

extern "C" void kernel_launch(void* const* d_in, const int* in_sizes, int n_in,
                              void* d_out, int out_size, void* d_ws, size_t ws_size,
                              hipStream_t stream) {
    const float* x       = (const float*)d_in[0];
    const float* centers = (const float*)d_in[1];
    const float* scaling = (const float*)d_in[2];

    const int nRows = in_sizes[0] / D;          // B*N = 65536
    float* O  = (float*)d_out;                  // nRows*K floats
    float* Hx = (float*)d_out + (size_t)nRows * K;

    const int grid = (nRows + ROWS_PER_BLOCK - 1) / ROWS_PER_BLOCK;  // 1024
    rbf_kernel<<<grid, BLOCK, 0, stream>>>(x, centers, scaling, O, Hx, nRows);
}

// Round 6
// 12.164 us; speedup vs baseline: 2.1518x; 2.1518x over previous
//
#include <hip/hip_runtime.h>

// RBFLayer: B=4, N=16384, D=16, K=64
//   s  = scaling[0,0,:,0]            (D,)
//   Hx = x * s                       (B,N,D)
//   O[b,n,k] = sum_d (Hx[b,n,d] - s[d]*centers[k,d])^2
// Outputs concatenated: O (B*N*K floats) then Hx (B*N*D floats).
//
// R2 structure (best measured: 12.8us) + non-temporal stores for the
// write-once O/Hx streams and non-temporal load for the read-once x.
// Uses clang ext_vector_type for the nontemporal builtins (HIP_vector_type
// float2/float4 wrappers are rejected by the builtin).

constexpr int D = 16;
constexpr int K = 64;
constexpr int ROWS_PER_BLOCK = 32;
constexpr int BLOCK = 256;

typedef float f32x2 __attribute__((ext_vector_type(2)));

__global__ __launch_bounds__(BLOCK) void rbf_kernel(
    const float* __restrict__ x,        // (rows, D)
    const float* __restrict__ centers,  // (K, D)
    const float* __restrict__ scaling,  // (D,)
    float* __restrict__ O,              // (rows, K)
    float* __restrict__ Hx,             // (rows, D)
    int nRows)
{
    const int tid  = threadIdx.x;
    const int lane = tid & 63;          // = center index k
    const int rgrp = tid >> 6;          // 0..3 row-group within block

    __shared__ float hx_sh[ROWS_PER_BLOCK * D];   // 2 KB

    const int blockRow0 = blockIdx.x * ROWS_PER_BLOCK;

    // ---- Staging: load x tile (512 floats, f32x2/thread), scale once,
    //      write to LDS and straight to global Hx (non-temporal). ----
    {
        const f32x2* xsrc = reinterpret_cast<const f32x2*>(x + (size_t)blockRow0 * D);
        const f32x2* s2p  = reinterpret_cast<const f32x2*>(scaling);
        f32x2 v  = __builtin_nontemporal_load(xsrc + tid);
        f32x2 s2 = s2p[tid & 7];
        f32x2 h = v * s2;
        reinterpret_cast<f32x2*>(hx_sh)[tid] = h;
        __builtin_nontemporal_store(h, reinterpret_cast<f32x2*>(Hx + (size_t)blockRow0 * D) + tid);
    }

    // ---- Per-lane scaled center row in registers (16 VGPRs). ----
    float cs[D];
    {
        const float4* c4 = reinterpret_cast<const float4*>(centers + lane * D);
        const float4* s4 = reinterpret_cast<const float4*>(scaling);
        #pragma unroll
        for (int q = 0; q < 4; ++q) {
            float4 cv = c4[q];
            float4 sv = s4[q];
            cs[4 * q + 0] = cv.x * sv.x;
            cs[4 * q + 1] = cv.y * sv.y;
            cs[4 * q + 2] = cv.z * sv.z;
            cs[4 * q + 3] = cv.w * sv.w;
        }
    }

    __syncthreads();

    // ---- Main loop: 8 iterations, one row per wave per iteration. ----
    const float4* hx4 = reinterpret_cast<const float4*>(hx_sh);
    #pragma unroll
    for (int r = 0; r < ROWS_PER_BLOCK / 4; ++r) {
        const int localRow = r * 4 + rgrp;
        const int row = blockRow0 + localRow;
        if (row >= nRows) break;

        float4 h0 = hx4[localRow * 4 + 0];
        float4 h1 = hx4[localRow * 4 + 1];
        float4 h2 = hx4[localRow * 4 + 2];
        float4 h3 = hx4[localRow * 4 + 3];

        float acc = 0.f;
        float d0;
        d0 = h0.x - cs[0];  acc = fmaf(d0, d0, acc);
        d0 = h0.y - cs[1];  acc = fmaf(d0, d0, acc);
        d0 = h0.z - cs[2];  acc = fmaf(d0, d0, acc);
        d0 = h0.w - cs[3];  acc = fmaf(d0, d0, acc);
        d0 = h1.x - cs[4];  acc = fmaf(d0, d0, acc);
        d0 = h1.y - cs[5];  acc = fmaf(d0, d0, acc);
        d0 = h1.z - cs[6];  acc = fmaf(d0, d0, acc);
        d0 = h1.w - cs[7];  acc = fmaf(d0, d0, acc);
        d0 = h2.x - cs[8];  acc = fmaf(d0, d0, acc);
        d0 = h2.y - cs[9];  acc = fmaf(d0, d0, acc);
        d0 = h2.z - cs[10]; acc = fmaf(d0, d0, acc);
        d0 = h2.w - cs[11]; acc = fmaf(d0, d0, acc);
        d0 = h3.x - cs[12]; acc = fmaf(d0, d0, acc);
        d0 = h3.y - cs[13]; acc = fmaf(d0, d0, acc);
        d0 = h3.z - cs[14]; acc = fmaf(d0, d0, acc);
        d0 = h3.w - cs[15]; acc = fmaf(d0, d0, acc);

        __builtin_nontemporal_store(acc, &O[(size_t)row * K + lane]);  // 256B/wave
    }
}

extern "C" void kernel_launch(void* const* d_in, const int* in_sizes, int n_in,
                              void* d_out, int out_size, void* d_ws, size_t ws_size,
                              hipStream_t stream) {
    const float* x       = (const float*)d_in[0];
    const float* centers = (const float*)d_in[1];
    const float* scaling = (const float*)d_in[2];

    const int nRows = in_sizes[0] / D;          // B*N = 65536
    float* O  = (float*)d_out;                  // nRows*K floats
    float* Hx = (float*)d_out + (size_t)nRows * K;

    const int grid = (nRows + ROWS_PER_BLOCK - 1) / ROWS_PER_BLOCK;  // 2048
    rbf_kernel<<<grid, BLOCK, 0, stream>>>(x, centers, scaling, O, Hx, nRows);
}

// Round 7
// 12.133 us; speedup vs baseline: 2.1572x; 1.0025x over previous
//
#include <hip/hip_runtime.h>

// RBFLayer: B=4, N=16384, D=16, K=64
//   s  = scaling[0,0,:,0]            (D,)
//   Hx = x * s                       (B,N,D)
//   O[b,n,k] = sum_d (Hx[b,n,d] - s[d]*centers[k,d])^2
// Outputs concatenated: O (B*N*K floats) then Hx (B*N*D floats).
//
// R6 structure (12.16us) + float4 staging (128 threads) + no row guard
// (grid*ROWS == nRows exactly). NT on all streamed global accesses.

constexpr int D = 16;
constexpr int K = 64;
constexpr int ROWS_PER_BLOCK = 32;
constexpr int BLOCK = 256;

typedef float f32x4 __attribute__((ext_vector_type(4)));

__global__ __launch_bounds__(BLOCK) void rbf_kernel(
    const float* __restrict__ x,        // (rows, D)
    const float* __restrict__ centers,  // (K, D)
    const float* __restrict__ scaling,  // (D,)
    float* __restrict__ O,              // (rows, K)
    float* __restrict__ Hx)             // (rows, D)
{
    const int tid  = threadIdx.x;
    const int lane = tid & 63;          // = center index k
    const int rgrp = tid >> 6;          // 0..3 row-group within block

    __shared__ float hx_sh[ROWS_PER_BLOCK * D];   // 2 KB

    const int blockRow0 = blockIdx.x * ROWS_PER_BLOCK;

    // ---- Staging: 512 floats = 128 x float4. Threads 0-127 stage. ----
    if (tid < 128) {
        const f32x4* xsrc = reinterpret_cast<const f32x4*>(x + (size_t)blockRow0 * D);
        const f32x4* s4p  = reinterpret_cast<const f32x4*>(scaling);
        f32x4 v  = __builtin_nontemporal_load(xsrc + tid);
        f32x4 sq = s4p[tid & 3];         // quarter of the 16-wide row
        f32x4 h = v * sq;
        reinterpret_cast<f32x4*>(hx_sh)[tid] = h;
        __builtin_nontemporal_store(h, reinterpret_cast<f32x4*>(Hx + (size_t)blockRow0 * D) + tid);
    }

    // ---- Per-lane scaled center row in registers (16 VGPRs). ----
    float cs[D];
    {
        const float4* c4 = reinterpret_cast<const float4*>(centers + lane * D);
        const float4* s4 = reinterpret_cast<const float4*>(scaling);
        #pragma unroll
        for (int q = 0; q < 4; ++q) {
            float4 cv = c4[q];
            float4 sv = s4[q];
            cs[4 * q + 0] = cv.x * sv.x;
            cs[4 * q + 1] = cv.y * sv.y;
            cs[4 * q + 2] = cv.z * sv.z;
            cs[4 * q + 3] = cv.w * sv.w;
        }
    }

    __syncthreads();

    // ---- Main loop: 8 iterations, one row per wave per iteration. ----
    const float4* hx4 = reinterpret_cast<const float4*>(hx_sh);
    #pragma unroll
    for (int r = 0; r < ROWS_PER_BLOCK / 4; ++r) {
        const int localRow = r * 4 + rgrp;
        const int row = blockRow0 + localRow;

        float4 h0 = hx4[localRow * 4 + 0];   // ds_read_b128 broadcast
        float4 h1 = hx4[localRow * 4 + 1];
        float4 h2 = hx4[localRow * 4 + 2];
        float4 h3 = hx4[localRow * 4 + 3];

        float acc = 0.f;
        float d0;
        d0 = h0.x - cs[0];  acc = fmaf(d0, d0, acc);
        d0 = h0.y - cs[1];  acc = fmaf(d0, d0, acc);
        d0 = h0.z - cs[2];  acc = fmaf(d0, d0, acc);
        d0 = h0.w - cs[3];  acc = fmaf(d0, d0, acc);
        d0 = h1.x - cs[4];  acc = fmaf(d0, d0, acc);
        d0 = h1.y - cs[5];  acc = fmaf(d0, d0, acc);
        d0 = h1.z - cs[6];  acc = fmaf(d0, d0, acc);
        d0 = h1.w - cs[7];  acc = fmaf(d0, d0, acc);
        d0 = h2.x - cs[8];  acc = fmaf(d0, d0, acc);
        d0 = h2.y - cs[9];  acc = fmaf(d0, d0, acc);
        d0 = h2.z - cs[10]; acc = fmaf(d0, d0, acc);
        d0 = h2.w - cs[11]; acc = fmaf(d0, d0, acc);
        d0 = h3.x - cs[12]; acc = fmaf(d0, d0, acc);
        d0 = h3.y - cs[13]; acc = fmaf(d0, d0, acc);
        d0 = h3.z - cs[14]; acc = fmaf(d0, d0, acc);
        d0 = h3.w - cs[15]; acc = fmaf(d0, d0, acc);

        __builtin_nontemporal_store(acc, &O[(size_t)row * K + lane]);  // 256B/wave
    }
}

extern "C" void kernel_launch(void* const* d_in, const int* in_sizes, int n_in,
                              void* d_out, int out_size, void* d_ws, size_t ws_size,
                              hipStream_t stream) {
    const float* x       = (const float*)d_in[0];
    const float* centers = (const float*)d_in[1];
    const float* scaling = (const float*)d_in[2];

    const int nRows = in_sizes[0] / D;          // B*N = 65536 (= 2048 * 32 exactly)
    float* O  = (float*)d_out;                  // nRows*K floats
    float* Hx = (float*)d_out + (size_t)nRows * K;

    const int grid = nRows / ROWS_PER_BLOCK;    // 2048
    rbf_kernel<<<grid, BLOCK, 0, stream>>>(x, centers, scaling, O, Hx);
}